// Round 14
// baseline (169.376 us; speedup 1.0000x reference)
//
#include <hip/hip_runtime.h>
#include <hip/hip_bf16.h>

#define NFEAT 128
#define NPB 16     // nodes per block in agg_gemm
#define P 256      // CSR-build blocks (hist/scatter slices; all CUs active)
#define MAXN 10240 // LDS histogram capacity (n_nodes must be <= this)
#define CAP 128    // fixed per-node CSR capacity (P(deg>128) ~ 1e-15 here)
#define KTILE 16   // W k-rows per LDS tile in agg_gemm (8 k-pairs)
#define CVT 64     // h->bf16 converter blocks in hist_weights

__device__ __forceinline__ unsigned short f2bf(float f) {   // RNE bf16
    const unsigned int u = __float_as_uint(f);
    return (unsigned short)((u + 0x7FFFu + ((u >> 16) & 1u)) >> 16);
}
__device__ __forceinline__ float bflo(unsigned int u) {
    return __uint_as_float(u << 16);
}
__device__ __forceinline__ float bfhi(unsigned int u) {
    return __uint_as_float(u & 0xFFFF0000u);
}

// ---------------------------------------------------------------------------
// K1: blocks [0,P): per-block LDS histogram of dst -> hist_u8[b][n].
// blocks [P,P+128): fuse weights into Wcat[384][128] (k-major) + btot.
// blocks [P+128,..+CVT): stream-convert h (fp32) -> hb (bf16, L2-resident).
// No global atomics.
// ---------------------------------------------------------------------------
__global__ __launch_bounds__(256) void hist_weights(
        const int* __restrict__ dst, unsigned char* __restrict__ hist,
        int n_edges, int n_nodes,
        const float* __restrict__ h, unsigned short* __restrict__ hb,
        const float* __restrict__ Ws, const float* __restrict__ Wn,
        const float* __restrict__ Wu,
        const float* __restrict__ Wsb, const float* __restrict__ Wnb,
        const float* __restrict__ Wub,
        const float* __restrict__ lin, const float* __restrict__ linb,
        float* __restrict__ Wcat, float* __restrict__ btot) {
    __shared__ int lh[MAXN];
    __shared__ float cs[NFEAT], cn[NFEAT], cu[NFEAT], bsum[NFEAT];
    const int tid = threadIdx.x;
    if (blockIdx.x < P) {
        const int b = blockIdx.x;
        for (int n = tid; n < n_nodes; n += 256) lh[n] = 0;
        __syncthreads();
        const int per = (n_edges + P - 1) / P;
        const int beg = b * per;
        const int end = min(beg + per, n_edges);
        for (int i = beg + tid * 4; i < end; i += 1024) {
            if (i + 4 <= end) {
                const int4 d4 = *(const int4*)(dst + i);
                atomicAdd(&lh[d4.x], 1);
                atomicAdd(&lh[d4.y], 1);
                atomicAdd(&lh[d4.z], 1);
                atomicAdd(&lh[d4.w], 1);
            } else {
                for (int k = i; k < end; ++k) atomicAdd(&lh[dst[k]], 1);
            }
        }
        __syncthreads();
        unsigned char* hrow = hist + (size_t)b * n_nodes;
        const int n4 = n_nodes >> 2;
        for (int q = tid; q < n4; q += 256) {
            const int n = q * 4;
            const unsigned int v = (unsigned int)(lh[n] & 255)
                                 | ((unsigned int)(lh[n + 1] & 255) << 8)
                                 | ((unsigned int)(lh[n + 2] & 255) << 16)
                                 | ((unsigned int)(lh[n + 3] & 255) << 24);
            ((unsigned int*)hrow)[q] = v;
        }
        for (int n = n4 * 4 + tid; n < n_nodes; n += 256)
            hrow[n] = (unsigned char)lh[n];
    } else if (blockIdx.x < P + NFEAT) {
        const int i = blockIdx.x - P;   // k index 0..127
        const int o = tid;              // only o<128 active
        if (o < NFEAT) {
            cs[o] = Ws[o * NFEAT + i];
            cn[o] = Wn[o * NFEAT + i];
            cu[o] = Wu[o * NFEAT + i];
            bsum[o] = Wsb[o] + Wnb[o] + Wub[o];
        }
        __syncthreads();
        if (o < NFEAT) {
            float a1 = 0.f, a2 = 0.f, a3 = 0.f, ab = 0.f;
            #pragma unroll 4
            for (int k = 0; k < NFEAT; ++k) {
                const float l = lin[o * NFEAT + k];
                a1 += l * cs[k];
                a2 += l * cn[k];
                a3 += l * cu[k];
                ab += l * bsum[k];
            }
            Wcat[(0 * NFEAT + i) * NFEAT + o] = a1;
            Wcat[(1 * NFEAT + i) * NFEAT + o] = a2;
            Wcat[(2 * NFEAT + i) * NFEAT + o] = a3;
            if (i == 0) btot[o] = ab + linb[o];
        }
    } else {
        // h -> bf16 conversion: thread handles 4 floats -> one uint2 store
        const int b = blockIdx.x - P - NFEAT;
        const size_t total4 = (size_t)n_nodes * (NFEAT / 4);
        for (size_t q = (size_t)b * 256 + tid; q < total4; q += (size_t)CVT * 256) {
            const float4 v = *(const float4*)(h + q * 4);
            uint2 o;
            o.x = (unsigned int)f2bf(v.x) | ((unsigned int)f2bf(v.y) << 16);
            o.y = (unsigned int)f2bf(v.z) | ((unsigned int)f2bf(v.w) << 16);
            *(uint2*)(hb + q * 4) = o;
        }
    }
}

// ---------------------------------------------------------------------------
// K2: column scan (u8). One lane per node, coalesced, 10K-way parallel.
// (R7/R10 lesson: keep as its own flat launch.)
// ---------------------------------------------------------------------------
__global__ void col_scan(const unsigned char* __restrict__ hist,
                         unsigned char* __restrict__ base,
                         int* __restrict__ cnt, int n_nodes) {
    const int node = blockIdx.x * blockDim.x + threadIdx.x;
    if (node >= n_nodes) return;
    int run = 0;
    #pragma unroll 8
    for (int b = 0; b < P; ++b) {
        const int h = hist[(size_t)b * n_nodes + node];
        base[(size_t)b * n_nodes + node] = (unsigned char)run;
        run += h;
    }
    cnt[node] = run;
}

// ---------------------------------------------------------------------------
// K3: scatter into fixed-capacity CSR via LDS cursors (no global atomics).
// ---------------------------------------------------------------------------
__global__ __launch_bounds__(256) void scatter_csr(
        const int* __restrict__ src, const int* __restrict__ dst,
        const float* __restrict__ e, const unsigned char* __restrict__ base,
        int2* __restrict__ eidx, int n_edges, int n_nodes) {
    __shared__ int lh[MAXN];
    const int tid = threadIdx.x;
    const int b = blockIdx.x;
    for (int n = tid; n < n_nodes; n += 256)
        lh[n] = n * CAP + (int)base[(size_t)b * n_nodes + n];
    __syncthreads();
    const int per = (n_edges + P - 1) / P;
    const int beg = b * per;
    const int end = min(beg + per, n_edges);
    for (int i = beg + tid * 4; i < end; i += 1024) {
        if (i + 4 <= end) {
            const int4 d4 = *(const int4*)(dst + i);
            const int4 s4 = *(const int4*)(src + i);
            const float4 e4 = *(const float4*)(e + i);
            int p0 = atomicAdd(&lh[d4.x], 1);
            int p1 = atomicAdd(&lh[d4.y], 1);
            int p2 = atomicAdd(&lh[d4.z], 1);
            int p3 = atomicAdd(&lh[d4.w], 1);
            if (p0 < (d4.x + 1) * CAP) eidx[p0] = make_int2(s4.x, __float_as_int(e4.x));
            if (p1 < (d4.y + 1) * CAP) eidx[p1] = make_int2(s4.y, __float_as_int(e4.y));
            if (p2 < (d4.z + 1) * CAP) eidx[p2] = make_int2(s4.z, __float_as_int(e4.z));
            if (p3 < (d4.w + 1) * CAP) eidx[p3] = make_int2(s4.w, __float_as_int(e4.w));
        } else {
            for (int k = i; k < end; ++k) {
                const int d = dst[k];
                const int pos = atomicAdd(&lh[d], 1);
                if (pos < (d + 1) * CAP)
                    eidx[pos] = make_int2(src[k], __float_as_int(e[k]));
            }
        }
    }
}

// ---------------------------------------------------------------------------
// K4: fused aggregate + GEMM, bf16 LDS tiles.
// Xsb (bf16 X, 12KB) + se (16KB, Wt overlay) + scnt -> ~28.7KB LDS.
// Gather: 8 half-waves x 2 nodes; lane hl owns feats [4hl,4hl+4); hb rows
// (256B bf16, L2-resident per R13); unroll-8 in-flight loads; means stored
// to Xsb[1]/Xsb[2] as bf16.
// GEMM: X read as uint4 (8 k/node), W staged as k-pair-packed bf16 uint4
// (2k x 4outs per read) -> 6 ds_read_b128 per 64 FMAs (2x fewer than R13,
// which was LDS-issue-bound at ~28us).
// ---------------------------------------------------------------------------
__global__ __launch_bounds__(256, 4) void agg_gemm(
        const float* __restrict__ h, const unsigned short* __restrict__ hb,
        const int2* __restrict__ eidx,
        const int* __restrict__ cnt, const float* __restrict__ Wcat,
        const float* __restrict__ btot, float* __restrict__ out, int n_nodes) {
    __shared__ unsigned short Xsb[3][NPB][NFEAT];  // 12 KB (bf16)
    __shared__ int2 se[NPB][CAP];                  // 16 KB, Wt overlay in GEMM
    __shared__ int scnt[NPB];
    unsigned int* Wtp = (unsigned int*)&se[0][0];  // [KTILE/2][NFEAT] = 4 KB
    const int tid = threadIdx.x;
    const int n0 = blockIdx.x * NPB;

    if (tid < NPB) scnt[tid] = (n0 + tid < n_nodes) ? cnt[n0 + tid] : 0;
    __syncthreads();

    for (int i = tid; i < NPB * CAP; i += 256) {
        const int ln = i >> 7;          // CAP = 128
        const int k  = i & (CAP - 1);
        if (k < scnt[ln]) se[ln][k] = eidx[(size_t)(n0 + ln) * CAP + k];
    }
    // stage h rows as bf16 into Xsb[0]
    for (int i = tid; i < NPB * (NFEAT / 4); i += 256) {
        const int n = i >> 5;
        const int c4 = i & 31;
        const int gn = n0 + n;
        float4 v = make_float4(0.f, 0.f, 0.f, 0.f);
        if (gn < n_nodes) v = *(const float4*)(h + (size_t)gn * NFEAT + c4 * 4);
        uint2 pk;
        pk.x = (unsigned int)f2bf(v.x) | ((unsigned int)f2bf(v.y) << 16);
        pk.y = (unsigned int)f2bf(v.z) | ((unsigned int)f2bf(v.w) << 16);
        *(uint2*)(&Xsb[0][n][c4 * 4]) = pk;
    }
    __syncthreads();

    {
        const int hw = tid >> 5;
        const int hl = tid & 31;
        const unsigned short* hbp = hb + hl * 4;
        #pragma unroll
        for (int t = 0; t < 2; ++t) {
            const int ln = hw * 2 + t;
            const int n = scnt[ln];
            const int nl = min(n, CAP);
            float4 su = make_float4(0.f, 0.f, 0.f, 0.f);
            float4 sp = make_float4(0.f, 0.f, 0.f, 0.f);
            int j = 0;
            for (; j + 8 <= nl; j += 8) {         // 8 row-loads in flight
                int2 E[8];
                #pragma unroll
                for (int q = 0; q < 8; ++q) E[q] = se[ln][j + q];
                uint2 H[8];
                #pragma unroll
                for (int q = 0; q < 8; ++q)
                    H[q] = *(const uint2*)(hbp + (size_t)E[q].x * NFEAT);
                #pragma unroll
                for (int q = 0; q < 8; ++q) {
                    const float v = __int_as_float(E[q].y);
                    const float h0 = bflo(H[q].x), h1 = bfhi(H[q].x);
                    const float h2 = bflo(H[q].y), h3 = bfhi(H[q].y);
                    su.x += h0; su.y += h1; su.z += h2; su.w += h3;
                    sp.x += v * h0; sp.y += v * h1;
                    sp.z += v * h2; sp.w += v * h3;
                }
            }
            for (; j < nl; ++j) {
                const int2 e0 = se[ln][j];
                const uint2 Hv = *(const uint2*)(hbp + (size_t)e0.x * NFEAT);
                const float v0 = __int_as_float(e0.y);
                const float h0 = bflo(Hv.x), h1 = bfhi(Hv.x);
                const float h2 = bflo(Hv.y), h3 = bfhi(Hv.y);
                su.x += h0; su.y += h1; su.z += h2; su.w += h3;
                sp.x += v0 * h0; sp.y += v0 * h1;
                sp.z += v0 * h2; sp.w += v0 * h3;
            }
            const float inv = 1.0f / fmaxf((float)n, 1.0f);
            uint2 pk;
            pk.x = (unsigned int)f2bf(sp.x * inv) | ((unsigned int)f2bf(sp.y * inv) << 16);
            pk.y = (unsigned int)f2bf(sp.z * inv) | ((unsigned int)f2bf(sp.w * inv) << 16);
            *(uint2*)(&Xsb[1][ln][hl * 4]) = pk;
            pk.x = (unsigned int)f2bf(su.x * inv) | ((unsigned int)f2bf(su.y * inv) << 16);
            pk.y = (unsigned int)f2bf(su.z * inv) | ((unsigned int)f2bf(su.w * inv) << 16);
            *(uint2*)(&Xsb[2][ln][hl * 4]) = pk;
        }
    }

    const int og = tid & 31;
    const int ng = tid >> 5;
    const int o4 = og * 4;
    float acc0[4] = {0.f, 0.f, 0.f, 0.f};
    float acc1[4] = {0.f, 0.f, 0.f, 0.f};
    const int nA = ng * 2, nB = ng * 2 + 1;

    for (int kt = 0; kt < 3 * NFEAT; kt += KTILE) {
        __syncthreads();  // 1st iter: retire se reads; later: retire Wtp reads
        {
            // stage packed W tile: thread -> one uint4 (1 k-pair x 4 outs)
            const int kp = tid >> 5;        // 0..7
            const int c4 = tid & 31;
            const float4 a = *(const float4*)(Wcat + (size_t)(kt + 2 * kp) * NFEAT + c4 * 4);
            const float4 b = *(const float4*)(Wcat + (size_t)(kt + 2 * kp + 1) * NFEAT + c4 * 4);
            uint4 w;
            w.x = (unsigned int)f2bf(a.x) | ((unsigned int)f2bf(b.x) << 16);
            w.y = (unsigned int)f2bf(a.y) | ((unsigned int)f2bf(b.y) << 16);
            w.z = (unsigned int)f2bf(a.z) | ((unsigned int)f2bf(b.z) << 16);
            w.w = (unsigned int)f2bf(a.w) | ((unsigned int)f2bf(b.w) << 16);
            *(uint4*)(&Wtp[kp * NFEAT + c4 * 4]) = w;
        }
        __syncthreads();
        const int s  = kt >> 7;
        const int kb = kt & 127;
        #pragma unroll
        for (int g = 0; g < 2; ++g) {     // two 8-k groups per tile
            const uint4 xa = *(const uint4*)(&Xsb[s][nA][kb + g * 8]);
            const uint4 xb = *(const uint4*)(&Xsb[s][nB][kb + g * 8]);
            float xaf[8], xbf[8];
            xaf[0] = bflo(xa.x); xaf[1] = bfhi(xa.x);
            xaf[2] = bflo(xa.y); xaf[3] = bfhi(xa.y);
            xaf[4] = bflo(xa.z); xaf[5] = bfhi(xa.z);
            xaf[6] = bflo(xa.w); xaf[7] = bfhi(xa.w);
            xbf[0] = bflo(xb.x); xbf[1] = bfhi(xb.x);
            xbf[2] = bflo(xb.y); xbf[3] = bfhi(xb.y);
            xbf[4] = bflo(xb.z); xbf[5] = bfhi(xb.z);
            xbf[6] = bflo(xb.w); xbf[7] = bfhi(xb.w);
            #pragma unroll
            for (int kp = 0; kp < 4; ++kp) {
                const uint4 w = *(const uint4*)(&Wtp[(g * 4 + kp) * NFEAT + o4]);
                const float w0l = bflo(w.x), w0h = bfhi(w.x);
                const float w1l = bflo(w.y), w1h = bfhi(w.y);
                const float w2l = bflo(w.z), w2h = bfhi(w.z);
                const float w3l = bflo(w.w), w3h = bfhi(w.w);
                const float xa0 = xaf[2 * kp], xa1 = xaf[2 * kp + 1];
                const float xb0 = xbf[2 * kp], xb1 = xbf[2 * kp + 1];
                acc0[0] += xa0 * w0l + xa1 * w0h;
                acc0[1] += xa0 * w1l + xa1 * w1h;
                acc0[2] += xa0 * w2l + xa1 * w2h;
                acc0[3] += xa0 * w3l + xa1 * w3h;
                acc1[0] += xb0 * w0l + xb1 * w0h;
                acc1[1] += xb0 * w1l + xb1 * w1h;
                acc1[2] += xb0 * w2l + xb1 * w2h;
                acc1[3] += xb0 * w3l + xb1 * w3h;
            }
        }
    }

    const float4 bt = *(const float4*)(btot + o4);
    if (n0 + nA < n_nodes) {
        float4 v = make_float4(acc0[0] + bt.x, acc0[1] + bt.y,
                               acc0[2] + bt.z, acc0[3] + bt.w);
        *(float4*)(out + (size_t)(n0 + nA) * NFEAT + o4) = v;
    }
    if (n0 + nB < n_nodes) {
        float4 v = make_float4(acc1[0] + bt.x, acc1[1] + bt.y,
                               acc1[2] + bt.z, acc1[3] + bt.w);
        *(float4*)(out + (size_t)(n0 + nB) * NFEAT + o4) = v;
    }
}

extern "C" void kernel_launch(void* const* d_in, const int* in_sizes, int n_in,
                              void* d_out, int out_size, void* d_ws, size_t ws_size,
                              hipStream_t stream) {
    const float* h     = (const float*)d_in[0];
    const float* e     = (const float*)d_in[1];
    const int*   src   = (const int*)d_in[2];
    const int*   dst   = (const int*)d_in[3];
    const float* Ws_w  = (const float*)d_in[4];
    const float* Ws_b  = (const float*)d_in[5];
    const float* Wn_w  = (const float*)d_in[6];
    const float* Wn_b  = (const float*)d_in[7];
    const float* Wu_w  = (const float*)d_in[8];
    const float* Wu_b  = (const float*)d_in[9];
    const float* lin_w = (const float*)d_in[10];
    const float* lin_b = (const float*)d_in[11];
    float* out = (float*)d_out;

    const int n_nodes = in_sizes[0] / NFEAT;
    const int n_edges = in_sizes[2];

    // ---- workspace layout ----
    char* ws = (char*)d_ws;
    float* Wcat = (float*)ws;            ws += 3 * NFEAT * NFEAT * 4;
    float* btot = (float*)ws;            ws += NFEAT * 4;
    int2*  eidx = (int2*)ws;             ws += (size_t)n_nodes * CAP * 8;
    int*   cnt  = (int*)ws;              ws += n_nodes * 4;
    unsigned short* hb = (unsigned short*)ws;  ws += (size_t)n_nodes * NFEAT * 2;
    unsigned char* hist = (unsigned char*)ws;  ws += (size_t)P * n_nodes;
    unsigned char* base = (unsigned char*)ws;  ws += (size_t)P * n_nodes;

    hist_weights<<<P + NFEAT + CVT, 256, 0, stream>>>(
        dst, hist, n_edges, n_nodes, h, hb,
        Ws_w, Wn_w, Wu_w, Ws_b, Wn_b, Wu_b, lin_w, lin_b, Wcat, btot);

    col_scan<<<(n_nodes + 255) / 256, 256, 0, stream>>>(hist, base, cnt, n_nodes);

    scatter_csr<<<P, 256, 0, stream>>>(src, dst, e, base, eidx, n_edges, n_nodes);

    const int n_blocks = (n_nodes + NPB - 1) / NPB;
    agg_gemm<<<n_blocks, 256, 0, stream>>>(h, hb, eidx, cnt, Wcat, btot,
                                           out, n_nodes);
}

// Round 15
// 137.809 us; speedup vs baseline: 1.2291x; 1.2291x over previous
//
#include <hip/hip_runtime.h>
#include <hip/hip_bf16.h>

#define NFEAT 128
#define NPB 16     // nodes per block in agg_gemm
#define P 256      // CSR-build blocks (hist/scatter slices; all CUs active)
#define MAXN 10240 // LDS histogram capacity (n_nodes must be <= this)
#define CAP 128    // fixed per-node CSR capacity (P(deg>128) ~ 1e-15 here)
#define CVT 64     // h->bf16 converter blocks in hist_weights

typedef __attribute__((ext_vector_type(8))) short bf16x8;
typedef __attribute__((ext_vector_type(4))) float f32x4;

__device__ __forceinline__ unsigned short f2bf(float f) {   // RNE bf16
    const unsigned int u = __float_as_uint(f);
    return (unsigned short)((u + 0x7FFFu + ((u >> 16) & 1u)) >> 16);
}
__device__ __forceinline__ float bflo(unsigned int u) {
    return __uint_as_float(u << 16);
}
__device__ __forceinline__ float bfhi(unsigned int u) {
    return __uint_as_float(u & 0xFFFF0000u);
}

// ---------------------------------------------------------------------------
// K1: blocks [0,P): per-block LDS histogram of dst -> hist_u8[b][n].
// blocks [P,P+128): fuse weights -> Wcatb in MFMA B-FRAGMENT ORDER (bf16):
//   element (r,o) of Wcat[384][128] lives at
//   ((tk*8 + tn)*64 + quad*16 + ncol)*8 + j,  tk=r>>5, quad=(r&31)>>3,
//   j=r&7, tn=o>>4, ncol=o&15 — so a wave's B fragment for tile (tk,tn) is
//   one contiguous 1KB chunk (16B/lane).  btot stays fp32.
// blocks [P+128,..+CVT): stream-convert h (fp32) -> hb (bf16, L2-resident).
// No global atomics.
// ---------------------------------------------------------------------------
__global__ __launch_bounds__(256) void hist_weights(
        const int* __restrict__ dst, unsigned char* __restrict__ hist,
        int n_edges, int n_nodes,
        const float* __restrict__ h, unsigned short* __restrict__ hb,
        const float* __restrict__ Ws, const float* __restrict__ Wn,
        const float* __restrict__ Wu,
        const float* __restrict__ Wsb, const float* __restrict__ Wnb,
        const float* __restrict__ Wub,
        const float* __restrict__ lin, const float* __restrict__ linb,
        unsigned short* __restrict__ Wcatb, float* __restrict__ btot) {
    __shared__ int lh[MAXN];
    __shared__ float cs[NFEAT], cn[NFEAT], cu[NFEAT], bsum[NFEAT];
    const int tid = threadIdx.x;
    if (blockIdx.x < P) {
        const int b = blockIdx.x;
        for (int n = tid; n < n_nodes; n += 256) lh[n] = 0;
        __syncthreads();
        const int per = (n_edges + P - 1) / P;
        const int beg = b * per;
        const int end = min(beg + per, n_edges);
        for (int i = beg + tid * 4; i < end; i += 1024) {
            if (i + 4 <= end) {
                const int4 d4 = *(const int4*)(dst + i);
                atomicAdd(&lh[d4.x], 1);
                atomicAdd(&lh[d4.y], 1);
                atomicAdd(&lh[d4.z], 1);
                atomicAdd(&lh[d4.w], 1);
            } else {
                for (int k = i; k < end; ++k) atomicAdd(&lh[dst[k]], 1);
            }
        }
        __syncthreads();
        unsigned char* hrow = hist + (size_t)b * n_nodes;
        const int n4 = n_nodes >> 2;
        for (int q = tid; q < n4; q += 256) {
            const int n = q * 4;
            const unsigned int v = (unsigned int)(lh[n] & 255)
                                 | ((unsigned int)(lh[n + 1] & 255) << 8)
                                 | ((unsigned int)(lh[n + 2] & 255) << 16)
                                 | ((unsigned int)(lh[n + 3] & 255) << 24);
            ((unsigned int*)hrow)[q] = v;
        }
        for (int n = n4 * 4 + tid; n < n_nodes; n += 256)
            hrow[n] = (unsigned char)lh[n];
    } else if (blockIdx.x < P + NFEAT) {
        const int i = blockIdx.x - P;   // k index 0..127 within each source
        const int o = tid;              // only o<128 active
        if (o < NFEAT) {
            cs[o] = Ws[o * NFEAT + i];
            cn[o] = Wn[o * NFEAT + i];
            cu[o] = Wu[o * NFEAT + i];
            bsum[o] = Wsb[o] + Wnb[o] + Wub[o];
        }
        __syncthreads();
        if (o < NFEAT) {
            float a1 = 0.f, a2 = 0.f, a3 = 0.f, ab = 0.f;
            #pragma unroll 4
            for (int k = 0; k < NFEAT; ++k) {
                const float l = lin[o * NFEAT + k];
                a1 += l * cs[k];
                a2 += l * cn[k];
                a3 += l * cu[k];
                ab += l * bsum[k];
            }
            const int tn = o >> 4, ncol = o & 15;
            const int kin = i & 31, quad = kin >> 3, j = kin & 7;
            const int tkbase = (i >> 5);          // 0..3 within a source
            const float av[3] = {a1, a2, a3};
            #pragma unroll
            for (int s = 0; s < 3; ++s) {
                const int tk = s * 4 + tkbase;    // 0..11
                const size_t idx =
                    ((size_t)(tk * 8 + tn) * 64 + quad * 16 + ncol) * 8 + j;
                Wcatb[idx] = f2bf(av[s]);
            }
            if (i == 0) btot[o] = ab + linb[o];
        }
    } else {
        // h -> bf16 conversion: thread handles 4 floats -> one uint2 store
        const int b = blockIdx.x - P - NFEAT;
        const size_t total4 = (size_t)n_nodes * (NFEAT / 4);
        for (size_t q = (size_t)b * 256 + tid; q < total4; q += (size_t)CVT * 256) {
            const float4 v = *(const float4*)(h + q * 4);
            uint2 o;
            o.x = (unsigned int)f2bf(v.x) | ((unsigned int)f2bf(v.y) << 16);
            o.y = (unsigned int)f2bf(v.z) | ((unsigned int)f2bf(v.w) << 16);
            *(uint2*)(hb + q * 4) = o;
        }
    }
}

// ---------------------------------------------------------------------------
// K2: column scan (u8). One lane per node, coalesced, 10K-way parallel.
// (R7/R10 lesson: keep as its own flat launch.)
// ---------------------------------------------------------------------------
__global__ void col_scan(const unsigned char* __restrict__ hist,
                         unsigned char* __restrict__ base,
                         int* __restrict__ cnt, int n_nodes) {
    const int node = blockIdx.x * blockDim.x + threadIdx.x;
    if (node >= n_nodes) return;
    int run = 0;
    #pragma unroll 8
    for (int b = 0; b < P; ++b) {
        const int h = hist[(size_t)b * n_nodes + node];
        base[(size_t)b * n_nodes + node] = (unsigned char)run;
        run += h;
    }
    cnt[node] = run;
}

// ---------------------------------------------------------------------------
// K3: scatter into fixed-capacity CSR via LDS cursors (no global atomics).
// ---------------------------------------------------------------------------
__global__ __launch_bounds__(256) void scatter_csr(
        const int* __restrict__ src, const int* __restrict__ dst,
        const float* __restrict__ e, const unsigned char* __restrict__ base,
        int2* __restrict__ eidx, int n_edges, int n_nodes) {
    __shared__ int lh[MAXN];
    const int tid = threadIdx.x;
    const int b = blockIdx.x;
    for (int n = tid; n < n_nodes; n += 256)
        lh[n] = n * CAP + (int)base[(size_t)b * n_nodes + n];
    __syncthreads();
    const int per = (n_edges + P - 1) / P;
    const int beg = b * per;
    const int end = min(beg + per, n_edges);
    for (int i = beg + tid * 4; i < end; i += 1024) {
        if (i + 4 <= end) {
            const int4 d4 = *(const int4*)(dst + i);
            const int4 s4 = *(const int4*)(src + i);
            const float4 e4 = *(const float4*)(e + i);
            int p0 = atomicAdd(&lh[d4.x], 1);
            int p1 = atomicAdd(&lh[d4.y], 1);
            int p2 = atomicAdd(&lh[d4.z], 1);
            int p3 = atomicAdd(&lh[d4.w], 1);
            if (p0 < (d4.x + 1) * CAP) eidx[p0] = make_int2(s4.x, __float_as_int(e4.x));
            if (p1 < (d4.y + 1) * CAP) eidx[p1] = make_int2(s4.y, __float_as_int(e4.y));
            if (p2 < (d4.z + 1) * CAP) eidx[p2] = make_int2(s4.z, __float_as_int(e4.z));
            if (p3 < (d4.w + 1) * CAP) eidx[p3] = make_int2(s4.w, __float_as_int(e4.w));
        } else {
            for (int k = i; k < end; ++k) {
                const int d = dst[k];
                const int pos = atomicAdd(&lh[d], 1);
                if (pos < (d + 1) * CAP)
                    eidx[pos] = make_int2(src[k], __float_as_int(e[k]));
            }
        }
    }
}

// ---------------------------------------------------------------------------
// K4: fused aggregate + MFMA GEMM.
// Gather (unchanged from R13): 8 half-waves x 2 nodes, bf16 hb rows
// (L2-resident), unroll-8, fp32 accumulate; means packed bf16 into Xsb.
// GEMM: per wave, 2 n-tiles x 12 k-tiles of mfma_f32_16x16x32_bf16.
//   A frag: ds_read_b128 from Xsb  (A[m=lane&15][k=quad*8+j])
//   B frag: coalesced 16B/lane global read of pre-swizzled Wcatb
//   D: col=lane&15, row=quad*4+reg  (HW-verified layouts per guide §3)
// ---------------------------------------------------------------------------
__global__ __launch_bounds__(256, 4) void agg_gemm(
        const float* __restrict__ h, const unsigned short* __restrict__ hb,
        const int2* __restrict__ eidx,
        const int* __restrict__ cnt, const unsigned short* __restrict__ Wcatb,
        const float* __restrict__ btot, float* __restrict__ out, int n_nodes) {
    __shared__ unsigned short Xsb[3][NPB][NFEAT];  // 12 KB (bf16)
    __shared__ int2 se[NPB][CAP];                  // 16 KB
    __shared__ int scnt[NPB];
    const int tid = threadIdx.x;
    const int n0 = blockIdx.x * NPB;

    if (tid < NPB) scnt[tid] = (n0 + tid < n_nodes) ? cnt[n0 + tid] : 0;
    __syncthreads();

    for (int i = tid; i < NPB * CAP; i += 256) {
        const int ln = i >> 7;          // CAP = 128
        const int k  = i & (CAP - 1);
        if (k < scnt[ln]) se[ln][k] = eidx[(size_t)(n0 + ln) * CAP + k];
    }
    // stage h rows as bf16 into Xsb[0]
    for (int i = tid; i < NPB * (NFEAT / 4); i += 256) {
        const int n = i >> 5;
        const int c4 = i & 31;
        const int gn = n0 + n;
        float4 v = make_float4(0.f, 0.f, 0.f, 0.f);
        if (gn < n_nodes) v = *(const float4*)(h + (size_t)gn * NFEAT + c4 * 4);
        uint2 pk;
        pk.x = (unsigned int)f2bf(v.x) | ((unsigned int)f2bf(v.y) << 16);
        pk.y = (unsigned int)f2bf(v.z) | ((unsigned int)f2bf(v.w) << 16);
        *(uint2*)(&Xsb[0][n][c4 * 4]) = pk;
    }
    __syncthreads();

    {   // ---- gather/aggregate phase ----
        const int hw = tid >> 5;
        const int hl = tid & 31;
        const unsigned short* hbp = hb + hl * 4;
        #pragma unroll
        for (int t = 0; t < 2; ++t) {
            const int ln = hw * 2 + t;
            const int n = scnt[ln];
            const int nl = min(n, CAP);
            float4 su = make_float4(0.f, 0.f, 0.f, 0.f);
            float4 sp = make_float4(0.f, 0.f, 0.f, 0.f);
            int j = 0;
            for (; j + 8 <= nl; j += 8) {         // 8 row-loads in flight
                int2 E[8];
                #pragma unroll
                for (int q = 0; q < 8; ++q) E[q] = se[ln][j + q];
                uint2 H[8];
                #pragma unroll
                for (int q = 0; q < 8; ++q)
                    H[q] = *(const uint2*)(hbp + (size_t)E[q].x * NFEAT);
                #pragma unroll
                for (int q = 0; q < 8; ++q) {
                    const float v = __int_as_float(E[q].y);
                    const float h0 = bflo(H[q].x), h1 = bfhi(H[q].x);
                    const float h2 = bflo(H[q].y), h3 = bfhi(H[q].y);
                    su.x += h0; su.y += h1; su.z += h2; su.w += h3;
                    sp.x += v * h0; sp.y += v * h1;
                    sp.z += v * h2; sp.w += v * h3;
                }
            }
            for (; j < nl; ++j) {
                const int2 e0 = se[ln][j];
                const uint2 Hv = *(const uint2*)(hbp + (size_t)e0.x * NFEAT);
                const float v0 = __int_as_float(e0.y);
                const float h0 = bflo(Hv.x), h1 = bfhi(Hv.x);
                const float h2 = bflo(Hv.y), h3 = bfhi(Hv.y);
                su.x += h0; su.y += h1; su.z += h2; su.w += h3;
                sp.x += v0 * h0; sp.y += v0 * h1;
                sp.z += v0 * h2; sp.w += v0 * h3;
            }
            const float inv = 1.0f / fmaxf((float)n, 1.0f);
            uint2 pk;
            pk.x = (unsigned int)f2bf(sp.x * inv) | ((unsigned int)f2bf(sp.y * inv) << 16);
            pk.y = (unsigned int)f2bf(sp.z * inv) | ((unsigned int)f2bf(sp.w * inv) << 16);
            *(uint2*)(&Xsb[1][ln][hl * 4]) = pk;
            pk.x = (unsigned int)f2bf(su.x * inv) | ((unsigned int)f2bf(su.y * inv) << 16);
            pk.y = (unsigned int)f2bf(su.z * inv) | ((unsigned int)f2bf(su.w * inv) << 16);
            *(uint2*)(&Xsb[2][ln][hl * 4]) = pk;
        }
    }
    __syncthreads();   // Xsb complete for all 16 nodes

    // ---- MFMA GEMM phase: wave wv handles n-tiles {2wv, 2wv+1} ----
    {
        const int wv   = tid >> 6;
        const int lane = tid & 63;
        const int mrow = lane & 15;
        const int quad = lane >> 4;
        const int tn0  = wv * 2;
        f32x4 acc0 = {0.f, 0.f, 0.f, 0.f};
        f32x4 acc1 = {0.f, 0.f, 0.f, 0.f};
        const bf16x8* Wb = (const bf16x8*)Wcatb;  // [(tk*8+tn)*64 + lane]
        #pragma unroll
        for (int tk = 0; tk < 12; ++tk) {
            const int s  = tk >> 2;
            const int kb = (tk & 3) * 32 + quad * 8;
            const bf16x8 a  = *(const bf16x8*)(&Xsb[s][mrow][kb]);
            const bf16x8 b0 = Wb[(size_t)(tk * 8 + tn0) * 64 + lane];
            const bf16x8 b1 = Wb[(size_t)(tk * 8 + tn0 + 1) * 64 + lane];
            acc0 = __builtin_amdgcn_mfma_f32_16x16x32_bf16(a, b0, acc0, 0, 0, 0);
            acc1 = __builtin_amdgcn_mfma_f32_16x16x32_bf16(a, b1, acc1, 0, 0, 0);
        }
        // epilogue: D col=lane&15, row=quad*4+r
        const int c0 = tn0 * 16 + mrow;
        const int c1 = (tn0 + 1) * 16 + mrow;
        const float bt0 = btot[c0];
        const float bt1 = btot[c1];
        #pragma unroll
        for (int r = 0; r < 4; ++r) {
            const int gn = n0 + quad * 4 + r;
            if (gn < n_nodes) {
                out[(size_t)gn * NFEAT + c0] = acc0[r] + bt0;
                out[(size_t)gn * NFEAT + c1] = acc1[r] + bt1;
            }
        }
    }
}

extern "C" void kernel_launch(void* const* d_in, const int* in_sizes, int n_in,
                              void* d_out, int out_size, void* d_ws, size_t ws_size,
                              hipStream_t stream) {
    const float* h     = (const float*)d_in[0];
    const float* e     = (const float*)d_in[1];
    const int*   src   = (const int*)d_in[2];
    const int*   dst   = (const int*)d_in[3];
    const float* Ws_w  = (const float*)d_in[4];
    const float* Ws_b  = (const float*)d_in[5];
    const float* Wn_w  = (const float*)d_in[6];
    const float* Wn_b  = (const float*)d_in[7];
    const float* Wu_w  = (const float*)d_in[8];
    const float* Wu_b  = (const float*)d_in[9];
    const float* lin_w = (const float*)d_in[10];
    const float* lin_b = (const float*)d_in[11];
    float* out = (float*)d_out;

    const int n_nodes = in_sizes[0] / NFEAT;
    const int n_edges = in_sizes[2];

    // ---- workspace layout ----
    char* ws = (char*)d_ws;
    unsigned short* Wcatb = (unsigned short*)ws;  ws += 3 * NFEAT * NFEAT * 2;
    float* btot = (float*)ws;            ws += NFEAT * 4;
    int2*  eidx = (int2*)ws;             ws += (size_t)n_nodes * CAP * 8;
    int*   cnt  = (int*)ws;              ws += n_nodes * 4;
    unsigned short* hb = (unsigned short*)ws;  ws += (size_t)n_nodes * NFEAT * 2;
    unsigned char* hist = (unsigned char*)ws;  ws += (size_t)P * n_nodes;
    unsigned char* base = (unsigned char*)ws;  ws += (size_t)P * n_nodes;

    hist_weights<<<P + NFEAT + CVT, 256, 0, stream>>>(
        dst, hist, n_edges, n_nodes, h, hb,
        Ws_w, Wn_w, Wu_w, Ws_b, Wn_b, Wu_b, lin_w, lin_b, Wcatb, btot);

    col_scan<<<(n_nodes + 255) / 256, 256, 0, stream>>>(hist, base, cnt, n_nodes);

    scatter_csr<<<P, 256, 0, stream>>>(src, dst, e, base, eidx, n_edges, n_nodes);

    const int n_blocks = (n_nodes + NPB - 1) / NPB;
    agg_gemm<<<n_blocks, 256, 0, stream>>>(h, hb, eidx, cnt, Wcatb, btot,
                                           out, n_nodes);
}

// Round 16
// 136.212 us; speedup vs baseline: 1.2435x; 1.0117x over previous
//
#include <hip/hip_runtime.h>
#include <hip/hip_bf16.h>

#define NFEAT 128
#define NPB 8      // nodes per block in agg_gemm (8 -> 1250 blocks, ~4.9/CU)
#define P 256      // CSR-build blocks (hist/scatter slices; all CUs active)
#define MAXN 10240 // LDS histogram capacity (n_nodes must be <= this)
#define CAP 128    // fixed per-node CSR capacity (P(deg>128) ~ 1e-15 here)
#define CVT 64     // h->bf16 converter blocks in hist_weights

typedef __attribute__((ext_vector_type(8))) short bf16x8;
typedef __attribute__((ext_vector_type(4))) float f32x4;

__device__ __forceinline__ unsigned short f2bf(float f) {   // RNE bf16
    const unsigned int u = __float_as_uint(f);
    return (unsigned short)((u + 0x7FFFu + ((u >> 16) & 1u)) >> 16);
}
__device__ __forceinline__ float bflo(unsigned int u) {
    return __uint_as_float(u << 16);
}
__device__ __forceinline__ float bfhi(unsigned int u) {
    return __uint_as_float(u & 0xFFFF0000u);
}

// ---------------------------------------------------------------------------
// K1: blocks [0,P): per-block LDS histogram of dst -> hist_u8[b][n].
// blocks [P,P+128): fuse weights -> Wcatb in MFMA B-FRAGMENT ORDER (bf16):
//   element (r,o) of Wcat[384][128] lives at
//   ((tk*8 + tn)*64 + quad*16 + ncol)*8 + j,  tk=r>>5, quad=(r&31)>>3,
//   j=r&7, tn=o>>4, ncol=o&15.  btot stays fp32.
// blocks [P+128,..+CVT): stream-convert h (fp32) -> hb (bf16, L2-resident).
// No global atomics.
// ---------------------------------------------------------------------------
__global__ __launch_bounds__(256) void hist_weights(
        const int* __restrict__ dst, unsigned char* __restrict__ hist,
        int n_edges, int n_nodes,
        const float* __restrict__ h, unsigned short* __restrict__ hb,
        const float* __restrict__ Ws, const float* __restrict__ Wn,
        const float* __restrict__ Wu,
        const float* __restrict__ Wsb, const float* __restrict__ Wnb,
        const float* __restrict__ Wub,
        const float* __restrict__ lin, const float* __restrict__ linb,
        unsigned short* __restrict__ Wcatb, float* __restrict__ btot) {
    __shared__ int lh[MAXN];
    __shared__ float cs[NFEAT], cn[NFEAT], cu[NFEAT], bsum[NFEAT];
    const int tid = threadIdx.x;
    if (blockIdx.x < P) {
        const int b = blockIdx.x;
        for (int n = tid; n < n_nodes; n += 256) lh[n] = 0;
        __syncthreads();
        const int per = (n_edges + P - 1) / P;
        const int beg = b * per;
        const int end = min(beg + per, n_edges);
        for (int i = beg + tid * 4; i < end; i += 1024) {
            if (i + 4 <= end) {
                const int4 d4 = *(const int4*)(dst + i);
                atomicAdd(&lh[d4.x], 1);
                atomicAdd(&lh[d4.y], 1);
                atomicAdd(&lh[d4.z], 1);
                atomicAdd(&lh[d4.w], 1);
            } else {
                for (int k = i; k < end; ++k) atomicAdd(&lh[dst[k]], 1);
            }
        }
        __syncthreads();
        unsigned char* hrow = hist + (size_t)b * n_nodes;
        const int n4 = n_nodes >> 2;
        for (int q = tid; q < n4; q += 256) {
            const int n = q * 4;
            const unsigned int v = (unsigned int)(lh[n] & 255)
                                 | ((unsigned int)(lh[n + 1] & 255) << 8)
                                 | ((unsigned int)(lh[n + 2] & 255) << 16)
                                 | ((unsigned int)(lh[n + 3] & 255) << 24);
            ((unsigned int*)hrow)[q] = v;
        }
        for (int n = n4 * 4 + tid; n < n_nodes; n += 256)
            hrow[n] = (unsigned char)lh[n];
    } else if (blockIdx.x < P + NFEAT) {
        const int i = blockIdx.x - P;   // k index 0..127 within each source
        const int o = tid;              // only o<128 active
        if (o < NFEAT) {
            cs[o] = Ws[o * NFEAT + i];
            cn[o] = Wn[o * NFEAT + i];
            cu[o] = Wu[o * NFEAT + i];
            bsum[o] = Wsb[o] + Wnb[o] + Wub[o];
        }
        __syncthreads();
        if (o < NFEAT) {
            float a1 = 0.f, a2 = 0.f, a3 = 0.f, ab = 0.f;
            #pragma unroll 4
            for (int k = 0; k < NFEAT; ++k) {
                const float l = lin[o * NFEAT + k];
                a1 += l * cs[k];
                a2 += l * cn[k];
                a3 += l * cu[k];
                ab += l * bsum[k];
            }
            const int tn = o >> 4, ncol = o & 15;
            const int kin = i & 31, quad = kin >> 3, j = kin & 7;
            const int tkbase = (i >> 5);          // 0..3 within a source
            const float av[3] = {a1, a2, a3};
            #pragma unroll
            for (int s = 0; s < 3; ++s) {
                const int tk = s * 4 + tkbase;    // 0..11
                const size_t idx =
                    ((size_t)(tk * 8 + tn) * 64 + quad * 16 + ncol) * 8 + j;
                Wcatb[idx] = f2bf(av[s]);
            }
            if (i == 0) btot[o] = ab + linb[o];
        }
    } else {
        // h -> bf16 conversion: thread handles 4 floats -> one uint2 store
        const int b = blockIdx.x - P - NFEAT;
        const size_t total4 = (size_t)n_nodes * (NFEAT / 4);
        for (size_t q = (size_t)b * 256 + tid; q < total4; q += (size_t)CVT * 256) {
            const float4 v = *(const float4*)(h + q * 4);
            uint2 o;
            o.x = (unsigned int)f2bf(v.x) | ((unsigned int)f2bf(v.y) << 16);
            o.y = (unsigned int)f2bf(v.z) | ((unsigned int)f2bf(v.w) << 16);
            *(uint2*)(hb + q * 4) = o;
        }
    }
}

// ---------------------------------------------------------------------------
// K2: column scan (u8). One lane per node, coalesced, 10K-way parallel.
// (R7/R10 lesson: keep as its own flat launch.)
// ---------------------------------------------------------------------------
__global__ void col_scan(const unsigned char* __restrict__ hist,
                         unsigned char* __restrict__ base,
                         int* __restrict__ cnt, int n_nodes) {
    const int node = blockIdx.x * blockDim.x + threadIdx.x;
    if (node >= n_nodes) return;
    int run = 0;
    #pragma unroll 8
    for (int b = 0; b < P; ++b) {
        const int h = hist[(size_t)b * n_nodes + node];
        base[(size_t)b * n_nodes + node] = (unsigned char)run;
        run += h;
    }
    cnt[node] = run;
}

// ---------------------------------------------------------------------------
// K3: scatter into fixed-capacity CSR via LDS cursors (no global atomics).
// ---------------------------------------------------------------------------
__global__ __launch_bounds__(256) void scatter_csr(
        const int* __restrict__ src, const int* __restrict__ dst,
        const float* __restrict__ e, const unsigned char* __restrict__ base,
        int2* __restrict__ eidx, int n_edges, int n_nodes) {
    __shared__ int lh[MAXN];
    const int tid = threadIdx.x;
    const int b = blockIdx.x;
    for (int n = tid; n < n_nodes; n += 256)
        lh[n] = n * CAP + (int)base[(size_t)b * n_nodes + n];
    __syncthreads();
    const int per = (n_edges + P - 1) / P;
    const int beg = b * per;
    const int end = min(beg + per, n_edges);
    for (int i = beg + tid * 4; i < end; i += 1024) {
        if (i + 4 <= end) {
            const int4 d4 = *(const int4*)(dst + i);
            const int4 s4 = *(const int4*)(src + i);
            const float4 e4 = *(const float4*)(e + i);
            int p0 = atomicAdd(&lh[d4.x], 1);
            int p1 = atomicAdd(&lh[d4.y], 1);
            int p2 = atomicAdd(&lh[d4.z], 1);
            int p3 = atomicAdd(&lh[d4.w], 1);
            if (p0 < (d4.x + 1) * CAP) eidx[p0] = make_int2(s4.x, __float_as_int(e4.x));
            if (p1 < (d4.y + 1) * CAP) eidx[p1] = make_int2(s4.y, __float_as_int(e4.y));
            if (p2 < (d4.z + 1) * CAP) eidx[p2] = make_int2(s4.z, __float_as_int(e4.z));
            if (p3 < (d4.w + 1) * CAP) eidx[p3] = make_int2(s4.w, __float_as_int(e4.w));
        } else {
            for (int k = i; k < end; ++k) {
                const int d = dst[k];
                const int pos = atomicAdd(&lh[d], 1);
                if (pos < (d + 1) * CAP)
                    eidx[pos] = make_int2(src[k], __float_as_int(e[k]));
            }
        }
    }
}

// ---------------------------------------------------------------------------
// K4: fused aggregate + MFMA GEMM, NPB=8 (grid 1250 -> ~4.9 blocks/CU;
// the gather is latency-bound and was grid-limited at 625 blocks).
// Gather: 8 half-waves x 1 node each, bf16 hb rows (L2-resident),
// unroll-8, fp32 accumulate; means packed bf16 into Xsb.
// GEMM: wave wv covers n-tiles {2wv,2wv+1}; A rows duplicated (mrow&7),
// stores masked to rows<8.  12 k-tiles of mfma_f32_16x16x32_bf16.
// ---------------------------------------------------------------------------
__global__ __launch_bounds__(256, 4) void agg_gemm(
        const float* __restrict__ h, const unsigned short* __restrict__ hb,
        const int2* __restrict__ eidx,
        const int* __restrict__ cnt, const unsigned short* __restrict__ Wcatb,
        const float* __restrict__ btot, float* __restrict__ out, int n_nodes) {
    __shared__ unsigned short Xsb[3][NPB][NFEAT];  // 6 KB (bf16)
    __shared__ int2 se[NPB][CAP];                  // 8 KB
    __shared__ int scnt[NPB];
    const int tid = threadIdx.x;
    const int n0 = blockIdx.x * NPB;

    if (tid < NPB) scnt[tid] = (n0 + tid < n_nodes) ? cnt[n0 + tid] : 0;
    __syncthreads();

    for (int i = tid; i < NPB * CAP; i += 256) {
        const int ln = i >> 7;          // CAP = 128
        const int k  = i & (CAP - 1);
        if (k < scnt[ln]) se[ln][k] = eidx[(size_t)(n0 + ln) * CAP + k];
    }
    // stage h rows as bf16 into Xsb[0]  (NPB*32 = 256 = one pass)
    {
        const int i = tid;
        const int n = i >> 5;
        const int c4 = i & 31;
        const int gn = n0 + n;
        float4 v = make_float4(0.f, 0.f, 0.f, 0.f);
        if (gn < n_nodes) v = *(const float4*)(h + (size_t)gn * NFEAT + c4 * 4);
        uint2 pk;
        pk.x = (unsigned int)f2bf(v.x) | ((unsigned int)f2bf(v.y) << 16);
        pk.y = (unsigned int)f2bf(v.z) | ((unsigned int)f2bf(v.w) << 16);
        *(uint2*)(&Xsb[0][n][c4 * 4]) = pk;
    }
    __syncthreads();

    {   // ---- gather/aggregate phase: half-wave hw owns node hw ----
        const int hw = tid >> 5;
        const int hl = tid & 31;
        const unsigned short* hbp = hb + hl * 4;
        const int ln = hw;
        const int n = scnt[ln];
        const int nl = min(n, CAP);
        float4 su = make_float4(0.f, 0.f, 0.f, 0.f);
        float4 sp = make_float4(0.f, 0.f, 0.f, 0.f);
        int j = 0;
        for (; j + 8 <= nl; j += 8) {         // 8 row-loads in flight
            int2 E[8];
            #pragma unroll
            for (int q = 0; q < 8; ++q) E[q] = se[ln][j + q];
            uint2 H[8];
            #pragma unroll
            for (int q = 0; q < 8; ++q)
                H[q] = *(const uint2*)(hbp + (size_t)E[q].x * NFEAT);
            #pragma unroll
            for (int q = 0; q < 8; ++q) {
                const float v = __int_as_float(E[q].y);
                const float h0 = bflo(H[q].x), h1 = bfhi(H[q].x);
                const float h2 = bflo(H[q].y), h3 = bfhi(H[q].y);
                su.x += h0; su.y += h1; su.z += h2; su.w += h3;
                sp.x += v * h0; sp.y += v * h1;
                sp.z += v * h2; sp.w += v * h3;
            }
        }
        for (; j < nl; ++j) {
            const int2 e0 = se[ln][j];
            const uint2 Hv = *(const uint2*)(hbp + (size_t)e0.x * NFEAT);
            const float v0 = __int_as_float(e0.y);
            const float h0 = bflo(Hv.x), h1 = bfhi(Hv.x);
            const float h2 = bflo(Hv.y), h3 = bfhi(Hv.y);
            su.x += h0; su.y += h1; su.z += h2; su.w += h3;
            sp.x += v0 * h0; sp.y += v0 * h1;
            sp.z += v0 * h2; sp.w += v0 * h3;
        }
        const float inv = 1.0f / fmaxf((float)n, 1.0f);
        uint2 pk;
        pk.x = (unsigned int)f2bf(sp.x * inv) | ((unsigned int)f2bf(sp.y * inv) << 16);
        pk.y = (unsigned int)f2bf(sp.z * inv) | ((unsigned int)f2bf(sp.w * inv) << 16);
        *(uint2*)(&Xsb[1][ln][hl * 4]) = pk;
        pk.x = (unsigned int)f2bf(su.x * inv) | ((unsigned int)f2bf(su.y * inv) << 16);
        pk.y = (unsigned int)f2bf(su.z * inv) | ((unsigned int)f2bf(su.w * inv) << 16);
        *(uint2*)(&Xsb[2][ln][hl * 4]) = pk;
    }
    __syncthreads();   // Xsb complete for all 8 nodes

    // ---- MFMA GEMM phase: wave wv handles n-tiles {2wv, 2wv+1} ----
    {
        const int wv   = tid >> 6;
        const int lane = tid & 63;
        const int mrow = lane & 15;
        const int quad = lane >> 4;
        const int tn0  = wv * 2;
        f32x4 acc0 = {0.f, 0.f, 0.f, 0.f};
        f32x4 acc1 = {0.f, 0.f, 0.f, 0.f};
        const bf16x8* Wb = (const bf16x8*)Wcatb;  // [(tk*8+tn)*64 + lane]
        #pragma unroll
        for (int tk = 0; tk < 12; ++tk) {
            const int s  = tk >> 2;
            const int kb = (tk & 3) * 32 + quad * 8;
            const bf16x8 a  = *(const bf16x8*)(&Xsb[s][mrow & 7][kb]);
            const bf16x8 b0 = Wb[(size_t)(tk * 8 + tn0) * 64 + lane];
            const bf16x8 b1 = Wb[(size_t)(tk * 8 + tn0 + 1) * 64 + lane];
            acc0 = __builtin_amdgcn_mfma_f32_16x16x32_bf16(a, b0, acc0, 0, 0, 0);
            acc1 = __builtin_amdgcn_mfma_f32_16x16x32_bf16(a, b1, acc1, 0, 0, 0);
        }
        // epilogue: D col=lane&15, row=quad*4+r; rows>=8 are duplicates
        const int c0 = tn0 * 16 + mrow;
        const int c1 = (tn0 + 1) * 16 + mrow;
        const float bt0 = btot[c0];
        const float bt1 = btot[c1];
        #pragma unroll
        for (int r = 0; r < 4; ++r) {
            const int row = quad * 4 + r;
            const int gn = n0 + row;
            if (row < NPB && gn < n_nodes) {
                out[(size_t)gn * NFEAT + c0] = acc0[r] + bt0;
                out[(size_t)gn * NFEAT + c1] = acc1[r] + bt1;
            }
        }
    }
}

extern "C" void kernel_launch(void* const* d_in, const int* in_sizes, int n_in,
                              void* d_out, int out_size, void* d_ws, size_t ws_size,
                              hipStream_t stream) {
    const float* h     = (const float*)d_in[0];
    const float* e     = (const float*)d_in[1];
    const int*   src   = (const int*)d_in[2];
    const int*   dst   = (const int*)d_in[3];
    const float* Ws_w  = (const float*)d_in[4];
    const float* Ws_b  = (const float*)d_in[5];
    const float* Wn_w  = (const float*)d_in[6];
    const float* Wn_b  = (const float*)d_in[7];
    const float* Wu_w  = (const float*)d_in[8];
    const float* Wu_b  = (const float*)d_in[9];
    const float* lin_w = (const float*)d_in[10];
    const float* lin_b = (const float*)d_in[11];
    float* out = (float*)d_out;

    const int n_nodes = in_sizes[0] / NFEAT;
    const int n_edges = in_sizes[2];

    // ---- workspace layout ----
    char* ws = (char*)d_ws;
    unsigned short* Wcatb = (unsigned short*)ws;  ws += 3 * NFEAT * NFEAT * 2;
    float* btot = (float*)ws;            ws += NFEAT * 4;
    int2*  eidx = (int2*)ws;             ws += (size_t)n_nodes * CAP * 8;
    int*   cnt  = (int*)ws;              ws += n_nodes * 4;
    unsigned short* hb = (unsigned short*)ws;  ws += (size_t)n_nodes * NFEAT * 2;
    unsigned char* hist = (unsigned char*)ws;  ws += (size_t)P * n_nodes;
    unsigned char* base = (unsigned char*)ws;  ws += (size_t)P * n_nodes;

    hist_weights<<<P + NFEAT + CVT, 256, 0, stream>>>(
        dst, hist, n_edges, n_nodes, h, hb,
        Ws_w, Wn_w, Wu_w, Ws_b, Wn_b, Wu_b, lin_w, lin_b, Wcatb, btot);

    col_scan<<<(n_nodes + 255) / 256, 256, 0, stream>>>(hist, base, cnt, n_nodes);

    scatter_csr<<<P, 256, 0, stream>>>(src, dst, e, base, eidx, n_edges, n_nodes);

    const int n_blocks = (n_nodes + NPB - 1) / NPB;
    agg_gemm<<<n_blocks, 256, 0, stream>>>(h, hb, eidx, cnt, Wcatb, btot,
                                           out, n_nodes);
}